// Round 4
// baseline (458.063 us; speedup 1.0000x reference)
//
#include <hip/hip_runtime.h>
#include <cstdint>
#include <cstddef>

typedef __attribute__((ext_vector_type(4))) float  floatx4;
typedef __attribute__((ext_vector_type(8))) __bf16 bf16x8;
typedef __attribute__((ext_vector_type(4))) __bf16 bf16x4;

#define B_   2
#define T_   2048
#define D_   2048
#define H_   16
#define DK   128
#define BT_  (B_ * T_)    // 4096 rows
#define N3   (3 * D_)     // 6144

// async global->LDS, 16B per lane. LDS dest must be (wave-uniform base + lane*16),
// which our slot indexing (s = i*256 + wave*64 + lane) guarantees.
__device__ __forceinline__ void async_copy16(const void* g, void* l) {
    __builtin_amdgcn_global_load_lds((const __attribute__((address_space(1))) void*)g,
                                     (__attribute__((address_space(3))) void*)l,
                                     16, 0, 0);
}

// ---------------------------------------------------------------------------
// prep kernels
// ---------------------------------------------------------------------------
__global__ void cast_bf16_kernel(const float* __restrict__ in, __bf16* __restrict__ out, int n4) {
    int i = blockIdx.x * 256 + threadIdx.x;
    if (i >= n4) return;
    float4 v = ((const float4*)in)[i];
    bf16x4 o;
    o.x = (__bf16)v.x; o.y = (__bf16)v.y; o.z = (__bf16)v.z; o.w = (__bf16)v.w;
    ((bf16x4*)out)[i] = o;
}

// in [R][C] fp32 -> out [C][R] bf16  (coalesced both sides via LDS tile)
__global__ void transcast_kernel(const float* __restrict__ in, __bf16* __restrict__ out, int R, int C) {
    __shared__ float tile[32][33];
    int c0 = blockIdx.x * 32, r0 = blockIdx.y * 32;
    int tx = threadIdx.x, ty = threadIdx.y;
#pragma unroll
    for (int j = 0; j < 32; j += 8)
        tile[ty + j][tx] = in[(size_t)(r0 + ty + j) * C + c0 + tx];
    __syncthreads();
#pragma unroll
    for (int j = 0; j < 32; j += 8)
        out[(size_t)(c0 + ty + j) * R + r0 + tx] = (__bf16)tile[tx][ty + j];
}

// kqv v-part [b*T+t][2D + h*128 + dd] -> VT [bh][dd][t]
__global__ void vtrans_kernel(const __bf16* __restrict__ kqv, __bf16* __restrict__ VT) {
    __shared__ __bf16 tile[32][33];
    int bh = blockIdx.z; int b = bh >> 4, h = bh & 15;
    int t0 = blockIdx.x * 32, d0 = blockIdx.y * 32;
    int tx = threadIdx.x, ty = threadIdx.y;
#pragma unroll
    for (int j = 0; j < 32; j += 8)
        tile[ty + j][tx] = kqv[(size_t)(b * T_ + t0 + ty + j) * N3 + 2 * D_ + h * DK + d0 + tx];
    __syncthreads();
#pragma unroll
    for (int j = 0; j < 32; j += 8)
        VT[(size_t)(bh * DK + d0 + ty + j) * T_ + t0 + tx] = tile[tx][ty + j];
}

// interleaved RoPE on k (cols [0,D)) and q (cols [D,2D)); writes [BH][T][128].
// q pre-scaled by log2(e)/sqrt(dk): fa's softmax then runs natively in base-2
// (exp2 == single v_exp_f32), mathematically identical weights.
__global__ void rope_kernel(const __bf16* __restrict__ kqv,
                            __bf16* __restrict__ Kh, __bf16* __restrict__ Qh) {
    int idx = blockIdx.x * 256 + threadIdx.x;   // 2^23 threads exactly
    int i     = idx & 63;              // pair index 0..63
    int t     = (idx >> 6) & (T_ - 1);
    int bh    = (idx >> 17) & 31;
    int which = idx >> 22;             // 0 = k, 1 = q
    int b = bh >> 4, h = bh & 15;
    const __bf16* src = kqv + (size_t)(b * T_ + t) * N3 + which * D_ + h * DK + 2 * i;
    float x1 = (float)src[0], x2 = (float)src[1];
    // inv_freq = 10000^(-2i/128) = 2^(-i * log2(10000)/64)
    float freq = exp2f((float)i * (-13.287712379549449f / 64.f));
    float ang = (float)t * freq;
    float sn, cn; sincosf(ang, &sn, &cn);
    float s = which ? 0.12751740f : 1.0f;   // log2(e)/sqrt(128) folded into q
    __bf16* dst = (which ? Qh : Kh) + (size_t)(bh * T_ + t) * DK + 2 * i;
    dst[0] = (__bf16)((x1 * cn - x2 * sn) * s);
    dst[1] = (__bf16)((x1 * sn + x2 * cn) * s);
}

// ---------------------------------------------------------------------------
// m97-style GEMM: C[M][N] = A[M][K] * BT[N][K]^T + bias[N]
// 128x128 tile, 4 waves (each 64x64 = 4x4 MFMA tiles), BK=32,
// global_load_lds width-16 staging, XOR chunk swizzle for conflict-free b128 reads.
// ---------------------------------------------------------------------------
template <typename OutT>
__global__ __launch_bounds__(256)
void gemm_bt(const __bf16* __restrict__ A, const __bf16* __restrict__ BTm,
             const float* __restrict__ bias, OutT* __restrict__ C,
             int M, int N, int K) {
    __shared__ __align__(16) __bf16 As[128 * 32];
    __shared__ __align__(16) __bf16 Bs[128 * 32];
    const int tid  = threadIdx.x;
    const int lane = tid & 63;
    const int wave = tid >> 6;
    const int quad = lane >> 4;
    const int l16  = lane & 15;
    const int m0 = blockIdx.y * 128;
    const int n0 = blockIdx.x * 128;
    const int wm = (wave & 1) * 64;
    const int wn = (wave >> 1) * 64;

    const floatx4 z4 = {0.f, 0.f, 0.f, 0.f};
    floatx4 acc[4][4];
#pragma unroll
    for (int i = 0; i < 4; ++i)
#pragma unroll
        for (int j = 0; j < 4; ++j) acc[i][j] = z4;

    int           sOff[2];
    const __bf16* gA[2];
    const __bf16* gB[2];
#pragma unroll
    for (int i = 0; i < 2; ++i) {
        int s = i * 256 + tid;
        int row = s >> 2, cs = s & 3;
        int gc = cs ^ ((row >> 1) & 3);
        sOff[i] = s * 8;
        gA[i] = A   + (size_t)(m0 + row) * K + gc * 8;
        gB[i] = BTm + (size_t)(n0 + row) * K + gc * 8;
    }

    for (int kt = 0; kt < K; kt += 32) {
        __syncthreads();
#pragma unroll
        for (int i = 0; i < 2; ++i) {
            async_copy16(gA[i] + kt, As + sOff[i]);
            async_copy16(gB[i] + kt, Bs + sOff[i]);
        }
        __syncthreads();
        bf16x8 af[4], bf[4];
#pragma unroll
        for (int t = 0; t < 4; ++t) {
            int rowA = wm + t * 16 + l16;
            int ca = quad ^ ((rowA >> 1) & 3);
            af[t] = *(const bf16x8*)(As + rowA * 32 + ca * 8);
            int rowB = wn + t * 16 + l16;
            int cb = quad ^ ((rowB >> 1) & 3);
            bf[t] = *(const bf16x8*)(Bs + rowB * 32 + cb * 8);
        }
#pragma unroll
        for (int mt = 0; mt < 4; ++mt)
#pragma unroll
            for (int nt = 0; nt < 4; ++nt)
                acc[mt][nt] = __builtin_amdgcn_mfma_f32_16x16x32_bf16(af[mt], bf[nt], acc[mt][nt], 0, 0, 0);
    }

#pragma unroll
    for (int nt = 0; nt < 4; ++nt) {
        int n = n0 + wn + nt * 16 + l16;
        float bv = bias[n];
#pragma unroll
        for (int mt = 0; mt < 4; ++mt)
#pragma unroll
            for (int r = 0; r < 4; ++r) {
                int m = m0 + wm + mt * 16 + quad * 4 + r;
                C[(size_t)m * N + n] = (OutT)(acc[mt][nt][r] + bv);
            }
    }
}

// ---------------------------------------------------------------------------
// flash attention, balanced sequential Q-tile pairing (block j -> tiles j, 31-j)
// with a software-pipelined K-loop:
//   - Ks double-buffered (32KB): K[kt+1] prefetch issued at top of iter kt,
//     drained one full iteration later -> fully hidden.
//   - Vs single-buffered: V[kt] issued right after B1, drained at B2 behind
//     QK+softmax -> mostly hidden.
//   - Ps is wave-private: no barrier needed around the P round-trip.
// LDS 56KB -> 2 blocks/CU. Softmax in base-2 (q pre-scaled by log2e/sqrt(dk)).
// ---------------------------------------------------------------------------
__global__ __launch_bounds__(256)
void fa_kernel(const __bf16* __restrict__ Qg, const __bf16* __restrict__ Kg,
               const __bf16* __restrict__ VTg, __bf16* __restrict__ Og) {
    __shared__ __align__(16) __bf16 Ks[2][64 * 128];   // 32KB
    __shared__ __align__(16) __bf16 Vs[128 * 64];      // 16KB
    __shared__ __align__(16) __bf16 Ps[4][16 * 64];    //  8KB
    const int tid  = threadIdx.x;
    const int lane = tid & 63, wave = tid >> 6;
    const int quad = lane >> 4, l16 = lane & 15;
    const int bh = blockIdx.y;
    const int j  = blockIdx.x;          // 0..15
    const int b = bh >> 4, h = bh & 15;

    const __bf16* Kb = Kg  + (size_t)bh * T_ * DK;
    const __bf16* Vb = VTg + (size_t)bh * DK * T_;
    __bf16* Psw = Ps[wave];

    const floatx4 z4 = {0.f, 0.f, 0.f, 0.f};

    for (int half = 0; half < 2; ++half) {
        const int qt = half ? (31 - j) : j;
        const int q0 = qt * 64;

        // ---- prologue: stage Q via Vs (free here) and K[0] into Ks[0] ----
        __syncthreads();   // previous half fully done with Ks/Vs
        {
            const __bf16* Qb = Qg + (size_t)(bh * T_ + q0) * DK;
#pragma unroll
            for (int i = 0; i < 4; ++i) {
                int s = i * 256 + tid;
                int row = s >> 4, cs = s & 15;
                int gc = cs ^ (row & 7);
                async_copy16(Qb + row * DK + gc * 8, Vs + s * 8);
                async_copy16(Kb + (size_t)row * DK + gc * 8, Ks[0] + s * 8);
            }
        }
        __syncthreads();   // Q and K[0] resident
        bf16x8 qf[4];
#pragma unroll
        for (int ks = 0; ks < 4; ++ks) {
            int row = wave * 16 + l16;
            int c = (ks * 4 + quad) ^ (row & 7);
            qf[ks] = *(const bf16x8*)(Vs + row * DK + c * 8);
        }

        float m_i[4], l_i[4];
        floatx4 accO[8];
#pragma unroll
        for (int r = 0; r < 4; ++r) { m_i[r] = -1e30f; l_i[r] = 0.f; }
#pragma unroll
        for (int nt = 0; nt < 8; ++nt) accO[nt] = z4;

        for (int kt = 0; kt <= qt; ++kt) {
            const int cur = kt & 1;
            // B1: closes PV(kt-1) (Vs free) / qf reads (kt==0); K[kt] prefetch
            // was issued a full iteration ago -> its drain here is cheap.
            __syncthreads();
            // issue V[kt] -> Vs (drained at B2, hidden behind QK+softmax)
#pragma unroll
            for (int i = 0; i < 4; ++i) {
                int s = i * 256 + tid;
                int row = s >> 3, cs = s & 7;   // Vs rows: 128B = 8 chunks
                int gc = cs ^ (row & 7);
                async_copy16(Vb + (size_t)row * T_ + kt * 64 + gc * 8, Vs + s * 8);
            }
            // prefetch K[kt+1] -> other buffer (drained by next iter's B1)
            if (kt < qt) {
#pragma unroll
                for (int i = 0; i < 4; ++i) {
                    int s = i * 256 + tid;
                    int row = s >> 4, cs = s & 15;
                    int gc = cs ^ (row & 7);
                    async_copy16(Kb + (size_t)((kt + 1) * 64 + row) * DK + gc * 8,
                                 Ks[cur ^ 1] + s * 8);
                }
            }

            // S strip 16x64 = Q_strip(16x128) . K_tile^T   (from Ks[cur])
            floatx4 sc[4];
#pragma unroll
            for (int nt = 0; nt < 4; ++nt) sc[nt] = z4;
#pragma unroll
            for (int ks = 0; ks < 4; ++ks)
#pragma unroll
                for (int nt = 0; nt < 4; ++nt) {
                    int row = nt * 16 + l16;
                    int c = (ks * 4 + quad) ^ (row & 7);
                    bf16x8 kf = *(const bf16x8*)(Ks[cur] + row * DK + c * 8);
                    sc[nt] = __builtin_amdgcn_mfma_f32_16x16x32_bf16(qf[ks], kf, sc[nt], 0, 0, 0);
                }

            // causal mask + row max (C layout: row = quad*4+r, col = nt*16+l16)
            float mnew[4] = {-1e30f, -1e30f, -1e30f, -1e30f};
            if (kt == qt) {
                const int qrow0 = q0 + wave * 16 + quad * 4;
#pragma unroll
                for (int nt = 0; nt < 4; ++nt) {
                    int kp = kt * 64 + nt * 16 + l16;
#pragma unroll
                    for (int r = 0; r < 4; ++r) {
                        float v = sc[nt][r];
                        v = (kp > qrow0 + r) ? -1e30f : v;
                        sc[nt][r] = v;
                        mnew[r] = fmaxf(mnew[r], v);
                    }
                }
            } else {
#pragma unroll
                for (int nt = 0; nt < 4; ++nt)
#pragma unroll
                    for (int r = 0; r < 4; ++r) mnew[r] = fmaxf(mnew[r], sc[nt][r]);
            }
#pragma unroll
            for (int r = 0; r < 4; ++r) {
                float v = mnew[r];
                v = fmaxf(v, __shfl_xor(v, 1));
                v = fmaxf(v, __shfl_xor(v, 2));
                v = fmaxf(v, __shfl_xor(v, 4));
                v = fmaxf(v, __shfl_xor(v, 8));
                mnew[r] = v;
            }
            float alpha[4];
#pragma unroll
            for (int r = 0; r < 4; ++r) {
                float mi = fmaxf(m_i[r], mnew[r]);
                alpha[r] = exp2f(m_i[r] - mi);   // base-2 softmax
                m_i[r] = mi;
            }
            float rs[4] = {0.f, 0.f, 0.f, 0.f};
#pragma unroll
            for (int nt = 0; nt < 4; ++nt)
#pragma unroll
                for (int r = 0; r < 4; ++r) {
                    float p = exp2f(sc[nt][r] - m_i[r]);
                    sc[nt][r] = p;
                    rs[r] += p;
                }
#pragma unroll
            for (int r = 0; r < 4; ++r) {
                float v = rs[r];
                v += __shfl_xor(v, 1);
                v += __shfl_xor(v, 2);
                v += __shfl_xor(v, 4);
                v += __shfl_xor(v, 8);
                l_i[r] = l_i[r] * alpha[r] + v;
            }
#pragma unroll
            for (int nt = 0; nt < 8; ++nt)
#pragma unroll
                for (int r = 0; r < 4; ++r) accO[nt][r] *= alpha[r];

            // B2: publishes Vs (V[kt] issued ~400cyc ago). Ps needs no barrier.
            __syncthreads();

            // P (C layout) -> LDS (A layout source), chunk-swizzled rows of 64 elems
#pragma unroll
            for (int nt = 0; nt < 4; ++nt) {
                int col = nt * 16 + l16;
                int ch = col >> 3, off = col & 7;
#pragma unroll
                for (int r = 0; r < 4; ++r) {
                    int row = quad * 4 + r;
                    Psw[row * 64 + (ch ^ (row & 7)) * 8 + off] = (__bf16)sc[nt][r];
                }
            }
            // O += P . V   (a from Psw, b from Vs = V^T rows)
#pragma unroll
            for (int ks2 = 0; ks2 < 2; ++ks2) {
                int ach = (ks2 * 4 + quad) ^ (l16 & 7);
                bf16x8 pf = *(const bf16x8*)(Psw + l16 * 64 + ach * 8);
#pragma unroll
                for (int nt = 0; nt < 8; ++nt) {
                    int vrow = nt * 16 + l16;
                    int vch = (ks2 * 4 + quad) ^ (vrow & 7);
                    bf16x8 vf = *(const bf16x8*)(Vs + vrow * 64 + vch * 8);
                    accO[nt] = __builtin_amdgcn_mfma_f32_16x16x32_bf16(pf, vf, accO[nt], 0, 0, 0);
                }
            }
        }

        // ---- epilogue for this tile ----
#pragma unroll
        for (int nt = 0; nt < 8; ++nt)
#pragma unroll
            for (int r = 0; r < 4; ++r) {
                int trow = q0 + wave * 16 + quad * 4 + r;
                int col = h * DK + nt * 16 + l16;
                Og[(size_t)(b * T_ + trow) * D_ + col] = (__bf16)(accO[nt][r] / l_i[r]);
            }
    }
}

// ---------------------------------------------------------------------------
extern "C" void kernel_launch(void* const* d_in, const int* in_sizes, int n_in,
                              void* d_out, int out_size, void* d_ws, size_t ws_size,
                              hipStream_t stream) {
    const float* x    = (const float*)d_in[0];
    const float* Wkqv = (const float*)d_in[1];
    const float* bkqv = (const float*)d_in[2];
    const float* Wo   = (const float*)d_in[3];
    const float* bo   = (const float*)d_in[4];
    float* out = (float*)d_out;

    // workspace layout (160 MiB total)
    char* p = (char*)d_ws;
    __bf16* xb    = (__bf16*)p; p += (size_t)BT_ * D_ * 2;  // 16 MiB
    __bf16* WkqvT = (__bf16*)p; p += (size_t)D_ * N3 * 2;   // 24 MiB
    __bf16* WoT   = (__bf16*)p; p += (size_t)D_ * D_ * 2;   //  8 MiB
    __bf16* kqv   = (__bf16*)p; p += (size_t)BT_ * N3 * 2;  // 48 MiB
    __bf16* qh    = (__bf16*)p; p += (size_t)BT_ * D_ * 2;  // 16 MiB
    __bf16* kh    = (__bf16*)p; p += (size_t)BT_ * D_ * 2;  // 16 MiB
    __bf16* vT    = (__bf16*)p; p += (size_t)BT_ * D_ * 2;  // 16 MiB
    __bf16* ao    = (__bf16*)p; p += (size_t)BT_ * D_ * 2;  // 16 MiB

    cast_bf16_kernel<<<(BT_ * D_ / 4 + 255) / 256, 256, 0, stream>>>(x, xb, BT_ * D_ / 4);
    transcast_kernel<<<dim3(N3 / 32, D_ / 32), dim3(32, 8), 0, stream>>>(Wkqv, WkqvT, D_, N3);
    transcast_kernel<<<dim3(D_ / 32, D_ / 32), dim3(32, 8), 0, stream>>>(Wo, WoT, D_, D_);
    gemm_bt<__bf16><<<dim3(N3 / 128, BT_ / 128), 256, 0, stream>>>(xb, WkqvT, bkqv, kqv, BT_, N3, D_);
    rope_kernel<<<(2 * 32 * T_ * 64) / 256, 256, 0, stream>>>(kqv, kh, qh);
    vtrans_kernel<<<dim3(T_ / 32, DK / 32, B_ * H_), dim3(32, 8), 0, stream>>>(kqv, vT);
    fa_kernel<<<dim3(16, B_ * H_), 256, 0, stream>>>(qh, kh, vT, ao);
    gemm_bt<float><<<dim3(D_ / 128, BT_ / 128), 256, 0, stream>>>(ao, WoT, bo, out, BT_, D_, D_);
}

// Round 5
// 424.224 us; speedup vs baseline: 1.0798x; 1.0798x over previous
//
#include <hip/hip_runtime.h>
#include <cstdint>
#include <cstddef>

typedef __attribute__((ext_vector_type(4))) float  floatx4;
typedef __attribute__((ext_vector_type(8))) __bf16 bf16x8;
typedef __attribute__((ext_vector_type(4))) __bf16 bf16x4;

#define B_   2
#define T_   2048
#define D_   2048
#define H_   16
#define DK   128
#define BT_  (B_ * T_)    // 4096 rows
#define N3   (3 * D_)     // 6144

// async global->LDS, 16B per lane. LDS dest must be (wave-uniform base + lane*16),
// which our slot indexing (s = i*256 + wave*64 + lane) guarantees.
__device__ __forceinline__ void async_copy16(const void* g, void* l) {
    __builtin_amdgcn_global_load_lds((const __attribute__((address_space(1))) void*)g,
                                     (__attribute__((address_space(3))) void*)l,
                                     16, 0, 0);
}

// ---------------------------------------------------------------------------
// prep kernels
// ---------------------------------------------------------------------------
__global__ void cast_bf16_kernel(const float* __restrict__ in, __bf16* __restrict__ out, int n4) {
    int i = blockIdx.x * 256 + threadIdx.x;
    if (i >= n4) return;
    float4 v = ((const float4*)in)[i];
    bf16x4 o;
    o.x = (__bf16)v.x; o.y = (__bf16)v.y; o.z = (__bf16)v.z; o.w = (__bf16)v.w;
    ((bf16x4*)out)[i] = o;
}

// in [R][C] fp32 -> out [C][R] bf16  (coalesced both sides via LDS tile)
__global__ void transcast_kernel(const float* __restrict__ in, __bf16* __restrict__ out, int R, int C) {
    __shared__ float tile[32][33];
    int c0 = blockIdx.x * 32, r0 = blockIdx.y * 32;
    int tx = threadIdx.x, ty = threadIdx.y;
#pragma unroll
    for (int j = 0; j < 32; j += 8)
        tile[ty + j][tx] = in[(size_t)(r0 + ty + j) * C + c0 + tx];
    __syncthreads();
#pragma unroll
    for (int j = 0; j < 32; j += 8)
        out[(size_t)(c0 + ty + j) * R + r0 + tx] = (__bf16)tile[tx][ty + j];
}

// kqv v-part [b*T+t][2D + h*128 + dd] -> VT [bh][dd][t]
__global__ void vtrans_kernel(const __bf16* __restrict__ kqv, __bf16* __restrict__ VT) {
    __shared__ __bf16 tile[32][33];
    int bh = blockIdx.z; int b = bh >> 4, h = bh & 15;
    int t0 = blockIdx.x * 32, d0 = blockIdx.y * 32;
    int tx = threadIdx.x, ty = threadIdx.y;
#pragma unroll
    for (int j = 0; j < 32; j += 8)
        tile[ty + j][tx] = kqv[(size_t)(b * T_ + t0 + ty + j) * N3 + 2 * D_ + h * DK + d0 + tx];
    __syncthreads();
#pragma unroll
    for (int j = 0; j < 32; j += 8)
        VT[(size_t)(bh * DK + d0 + ty + j) * T_ + t0 + tx] = tile[tx][ty + j];
}

// interleaved RoPE on k (cols [0,D)) and q (cols [D,2D)); writes [BH][T][128].
// q pre-scaled by log2(e)/sqrt(dk): fa's softmax then runs natively in base-2
// (exp2 == single v_exp_f32), mathematically identical weights.
__global__ void rope_kernel(const __bf16* __restrict__ kqv,
                            __bf16* __restrict__ Kh, __bf16* __restrict__ Qh) {
    int idx = blockIdx.x * 256 + threadIdx.x;   // 2^23 threads exactly
    int i     = idx & 63;              // pair index 0..63
    int t     = (idx >> 6) & (T_ - 1);
    int bh    = (idx >> 17) & 31;
    int which = idx >> 22;             // 0 = k, 1 = q
    int b = bh >> 4, h = bh & 15;
    const __bf16* src = kqv + (size_t)(b * T_ + t) * N3 + which * D_ + h * DK + 2 * i;
    float x1 = (float)src[0], x2 = (float)src[1];
    // inv_freq = 10000^(-2i/128) = 2^(-i * log2(10000)/64)
    float freq = exp2f((float)i * (-13.287712379549449f / 64.f));
    float ang = (float)t * freq;
    float sn, cn; sincosf(ang, &sn, &cn);
    float s = which ? 0.12751740f : 1.0f;   // log2(e)/sqrt(128) folded into q
    __bf16* dst = (which ? Qh : Kh) + (size_t)(bh * T_ + t) * DK + 2 * i;
    dst[0] = (__bf16)((x1 * cn - x2 * sn) * s);
    dst[1] = (__bf16)((x1 * sn + x2 * cn) * s);
}

// ---------------------------------------------------------------------------
// m97-style GEMM, BK=64: C[M][N] = A[M][K] * BT[N][K]^T + bias[N]
// 128x128 tile, 4 waves (each 64x64 = 4x4 MFMA tiles), BK=64 (32KB LDS total,
// half the barrier-drains of BK=32), global_load_lds width-16 staging,
// XOR chunk swizzle for conflict-free b128 reads. Fragments for the two
// K-halves are loaded sequentially to keep VGPR pressure at the BK=32 level.
// ---------------------------------------------------------------------------
template <typename OutT>
__global__ __launch_bounds__(256)
void gemm_bt(const __bf16* __restrict__ A, const __bf16* __restrict__ BTm,
             const float* __restrict__ bias, OutT* __restrict__ C,
             int M, int N, int K) {
    __shared__ __align__(16) __bf16 As[128 * 64];   // 16KB
    __shared__ __align__(16) __bf16 Bs[128 * 64];   // 16KB
    const int tid  = threadIdx.x;
    const int lane = tid & 63;
    const int wave = tid >> 6;
    const int quad = lane >> 4;
    const int l16  = lane & 15;
    const int m0 = blockIdx.y * 128;
    const int n0 = blockIdx.x * 128;
    const int wm = (wave & 1) * 64;
    const int wn = (wave >> 1) * 64;

    const floatx4 z4 = {0.f, 0.f, 0.f, 0.f};
    floatx4 acc[4][4];
#pragma unroll
    for (int i = 0; i < 4; ++i)
#pragma unroll
        for (int j = 0; j < 4; ++j) acc[i][j] = z4;

    // staging: 1024 slots of 16B per matrix; slot s -> row=s>>3, stored chunk
    // cs=s&7, holds global chunk gc = cs ^ (row&7)  (row stride 64 elems)
    int           sOff[4];
    const __bf16* gA[4];
    const __bf16* gB[4];
#pragma unroll
    for (int i = 0; i < 4; ++i) {
        int s = i * 256 + tid;
        int row = s >> 3, cs = s & 7;
        int gc = cs ^ (row & 7);
        sOff[i] = s * 8;
        gA[i] = A   + (size_t)(m0 + row) * K + gc * 8;
        gB[i] = BTm + (size_t)(n0 + row) * K + gc * 8;
    }

    for (int kt = 0; kt < K; kt += 64) {
        __syncthreads();
#pragma unroll
        for (int i = 0; i < 4; ++i) {
            async_copy16(gA[i] + kt, As + sOff[i]);
            async_copy16(gB[i] + kt, Bs + sOff[i]);
        }
        __syncthreads();
#pragma unroll
        for (int ks2 = 0; ks2 < 2; ++ks2) {
            bf16x8 af[4], bf[4];
#pragma unroll
            for (int t = 0; t < 4; ++t) {
                int rowA = wm + t * 16 + l16;
                int ca = (ks2 * 4 + quad) ^ (rowA & 7);
                af[t] = *(const bf16x8*)(As + rowA * 64 + ca * 8);
                int rowB = wn + t * 16 + l16;
                int cb = (ks2 * 4 + quad) ^ (rowB & 7);
                bf[t] = *(const bf16x8*)(Bs + rowB * 64 + cb * 8);
            }
#pragma unroll
            for (int mt = 0; mt < 4; ++mt)
#pragma unroll
                for (int nt = 0; nt < 4; ++nt)
                    acc[mt][nt] = __builtin_amdgcn_mfma_f32_16x16x32_bf16(af[mt], bf[nt], acc[mt][nt], 0, 0, 0);
        }
    }

#pragma unroll
    for (int nt = 0; nt < 4; ++nt) {
        int n = n0 + wn + nt * 16 + l16;
        float bv = bias[n];
#pragma unroll
        for (int mt = 0; mt < 4; ++mt)
#pragma unroll
            for (int r = 0; r < 4; ++r) {
                int m = m0 + wm + mt * 16 + quad * 4 + r;
                C[(size_t)m * N + n] = (OutT)(acc[mt][nt][r] + bv);
            }
    }
}

// ---------------------------------------------------------------------------
// flash attention, balanced via SEQUENTIAL Q-tile pairing (R3 structure):
// block j processes Q tile j fully, then tile 31-j, with single-strip register
// state (no spills). Every block = exactly 33 strip-iterations.
// 512 blocks, LDS 40KB (Ks 16K + Vs 16K + Ps 8K). Softmax in base-2
// (q pre-scaled by log2e/sqrt(dk) in rope_kernel).
// ---------------------------------------------------------------------------
__global__ __launch_bounds__(256)
void fa_kernel(const __bf16* __restrict__ Qg, const __bf16* __restrict__ Kg,
               const __bf16* __restrict__ VTg, __bf16* __restrict__ Og) {
    __shared__ __align__(16) __bf16 Ks[64 * 128];
    __shared__ __align__(16) __bf16 Vs[128 * 64];
    __shared__ __align__(16) __bf16 Ps[4][16 * 64];
    const int tid  = threadIdx.x;
    const int lane = tid & 63, wave = tid >> 6;
    const int quad = lane >> 4, l16 = lane & 15;
    const int bh = blockIdx.y;
    const int j  = blockIdx.x;          // 0..15
    const int b = bh >> 4, h = bh & 15;

    const __bf16* Kb = Kg  + (size_t)bh * T_ * DK;
    const __bf16* Vb = VTg + (size_t)bh * DK * T_;
    __bf16* Psw = Ps[wave];

    const floatx4 z4 = {0.f, 0.f, 0.f, 0.f};

    for (int half = 0; half < 2; ++half) {
        const int qt = half ? (31 - j) : j;
        const int q0 = qt * 64;

        // ---- prologue: stage Q tile through Ks, lift to registers ----
        __syncthreads();   // WAR: previous half's reads of Ks
        {
            const __bf16* Qb = Qg + (size_t)(bh * T_ + q0) * DK;
#pragma unroll
            for (int i = 0; i < 4; ++i) {
                int s = i * 256 + tid;
                int row = s >> 4, cs = s & 15;
                int gc = cs ^ (row & 7);
                async_copy16(Qb + row * DK + gc * 8, Ks + s * 8);
            }
        }
        __syncthreads();
        bf16x8 qf[4];
#pragma unroll
        for (int ks = 0; ks < 4; ++ks) {
            int row = wave * 16 + l16;
            int c = (ks * 4 + quad) ^ (row & 7);
            qf[ks] = *(const bf16x8*)(Ks + row * DK + c * 8);
        }

        float m_i[4], l_i[4];
        floatx4 accO[8];
#pragma unroll
        for (int r = 0; r < 4; ++r) { m_i[r] = -1e30f; l_i[r] = 0.f; }
#pragma unroll
        for (int nt = 0; nt < 8; ++nt) accO[nt] = z4;

        for (int kt = 0; kt <= qt; ++kt) {
            __syncthreads();   // WAR on Ks/Vs (also covers prologue qf reads)
#pragma unroll
            for (int i = 0; i < 4; ++i) {
                int s = i * 256 + tid;
                int row = s >> 4, cs = s & 15;
                int gc = cs ^ (row & 7);
                async_copy16(Kb + (size_t)(kt * 64 + row) * DK + gc * 8, Ks + s * 8);
            }
#pragma unroll
            for (int i = 0; i < 4; ++i) {
                int s = i * 256 + tid;
                int row = s >> 3, cs = s & 7;   // Vs rows: 128B = 8 chunks
                int gc = cs ^ (row & 7);
                async_copy16(Vb + (size_t)row * T_ + kt * 64 + gc * 8, Vs + s * 8);
            }
            __syncthreads();

            // S strip 16x64 = Q_strip(16x128) . K_tile^T
            floatx4 sc[4];
#pragma unroll
            for (int nt = 0; nt < 4; ++nt) sc[nt] = z4;
#pragma unroll
            for (int ks = 0; ks < 4; ++ks)
#pragma unroll
                for (int nt = 0; nt < 4; ++nt) {
                    int row = nt * 16 + l16;
                    int c = (ks * 4 + quad) ^ (row & 7);
                    bf16x8 kf = *(const bf16x8*)(Ks + row * DK + c * 8);
                    sc[nt] = __builtin_amdgcn_mfma_f32_16x16x32_bf16(qf[ks], kf, sc[nt], 0, 0, 0);
                }

            // causal mask + row max (C layout: row = quad*4+r, col = nt*16+l16)
            float mnew[4] = {-1e30f, -1e30f, -1e30f, -1e30f};
            if (kt == qt) {
                const int qrow0 = q0 + wave * 16 + quad * 4;
#pragma unroll
                for (int nt = 0; nt < 4; ++nt) {
                    int kp = kt * 64 + nt * 16 + l16;
#pragma unroll
                    for (int r = 0; r < 4; ++r) {
                        float v = sc[nt][r];
                        v = (kp > qrow0 + r) ? -1e30f : v;
                        sc[nt][r] = v;
                        mnew[r] = fmaxf(mnew[r], v);
                    }
                }
            } else {
#pragma unroll
                for (int nt = 0; nt < 4; ++nt)
#pragma unroll
                    for (int r = 0; r < 4; ++r) mnew[r] = fmaxf(mnew[r], sc[nt][r]);
            }
#pragma unroll
            for (int r = 0; r < 4; ++r) {
                float v = mnew[r];
                v = fmaxf(v, __shfl_xor(v, 1));
                v = fmaxf(v, __shfl_xor(v, 2));
                v = fmaxf(v, __shfl_xor(v, 4));
                v = fmaxf(v, __shfl_xor(v, 8));
                mnew[r] = v;
            }
            float alpha[4];
#pragma unroll
            for (int r = 0; r < 4; ++r) {
                float mi = fmaxf(m_i[r], mnew[r]);
                alpha[r] = exp2f(m_i[r] - mi);   // base-2 softmax
                m_i[r] = mi;
            }
            float rs[4] = {0.f, 0.f, 0.f, 0.f};
#pragma unroll
            for (int nt = 0; nt < 4; ++nt)
#pragma unroll
                for (int r = 0; r < 4; ++r) {
                    float p = exp2f(sc[nt][r] - m_i[r]);
                    sc[nt][r] = p;
                    rs[r] += p;
                }
#pragma unroll
            for (int r = 0; r < 4; ++r) {
                float v = rs[r];
                v += __shfl_xor(v, 1);
                v += __shfl_xor(v, 2);
                v += __shfl_xor(v, 4);
                v += __shfl_xor(v, 8);
                l_i[r] = l_i[r] * alpha[r] + v;
            }
#pragma unroll
            for (int nt = 0; nt < 8; ++nt)
#pragma unroll
                for (int r = 0; r < 4; ++r) accO[nt][r] *= alpha[r];

            // P (C layout) -> LDS (A layout source), chunk-swizzled rows of 64 elems
#pragma unroll
            for (int nt = 0; nt < 4; ++nt) {
                int col = nt * 16 + l16;
                int ch = col >> 3, off = col & 7;
#pragma unroll
                for (int r = 0; r < 4; ++r) {
                    int row = quad * 4 + r;
                    Psw[row * 64 + (ch ^ (row & 7)) * 8 + off] = (__bf16)sc[nt][r];
                }
            }
            // O += P . V   (a from Psw, b from Vs = V^T rows)
#pragma unroll
            for (int ks2 = 0; ks2 < 2; ++ks2) {
                int ach = (ks2 * 4 + quad) ^ (l16 & 7);
                bf16x8 pf = *(const bf16x8*)(Psw + l16 * 64 + ach * 8);
#pragma unroll
                for (int nt = 0; nt < 8; ++nt) {
                    int vrow = nt * 16 + l16;
                    int vch = (ks2 * 4 + quad) ^ (vrow & 7);
                    bf16x8 vf = *(const bf16x8*)(Vs + vrow * 64 + vch * 8);
                    accO[nt] = __builtin_amdgcn_mfma_f32_16x16x32_bf16(pf, vf, accO[nt], 0, 0, 0);
                }
            }
        }

        // ---- epilogue for this tile ----
#pragma unroll
        for (int nt = 0; nt < 8; ++nt)
#pragma unroll
            for (int r = 0; r < 4; ++r) {
                int trow = q0 + wave * 16 + quad * 4 + r;
                int col = h * DK + nt * 16 + l16;
                Og[(size_t)(b * T_ + trow) * D_ + col] = (__bf16)(accO[nt][r] / l_i[r]);
            }
    }
}

// ---------------------------------------------------------------------------
extern "C" void kernel_launch(void* const* d_in, const int* in_sizes, int n_in,
                              void* d_out, int out_size, void* d_ws, size_t ws_size,
                              hipStream_t stream) {
    const float* x    = (const float*)d_in[0];
    const float* Wkqv = (const float*)d_in[1];
    const float* bkqv = (const float*)d_in[2];
    const float* Wo   = (const float*)d_in[3];
    const float* bo   = (const float*)d_in[4];
    float* out = (float*)d_out;

    // workspace layout (160 MiB total)
    char* p = (char*)d_ws;
    __bf16* xb    = (__bf16*)p; p += (size_t)BT_ * D_ * 2;  // 16 MiB
    __bf16* WkqvT = (__bf16*)p; p += (size_t)D_ * N3 * 2;   // 24 MiB
    __bf16* WoT   = (__bf16*)p; p += (size_t)D_ * D_ * 2;   //  8 MiB
    __bf16* kqv   = (__bf16*)p; p += (size_t)BT_ * N3 * 2;  // 48 MiB
    __bf16* qh    = (__bf16*)p; p += (size_t)BT_ * D_ * 2;  // 16 MiB
    __bf16* kh    = (__bf16*)p; p += (size_t)BT_ * D_ * 2;  // 16 MiB
    __bf16* vT    = (__bf16*)p; p += (size_t)BT_ * D_ * 2;  // 16 MiB
    __bf16* ao    = (__bf16*)p; p += (size_t)BT_ * D_ * 2;  // 16 MiB

    cast_bf16_kernel<<<(BT_ * D_ / 4 + 255) / 256, 256, 0, stream>>>(x, xb, BT_ * D_ / 4);
    transcast_kernel<<<dim3(N3 / 32, D_ / 32), dim3(32, 8), 0, stream>>>(Wkqv, WkqvT, D_, N3);
    transcast_kernel<<<dim3(D_ / 32, D_ / 32), dim3(32, 8), 0, stream>>>(Wo, WoT, D_, D_);
    gemm_bt<__bf16><<<dim3(N3 / 128, BT_ / 128), 256, 0, stream>>>(xb, WkqvT, bkqv, kqv, BT_, N3, D_);
    rope_kernel<<<(2 * 32 * T_ * 64) / 256, 256, 0, stream>>>(kqv, kh, qh);
    vtrans_kernel<<<dim3(T_ / 32, DK / 32, B_ * H_), dim3(32, 8), 0, stream>>>(kqv, vT);
    fa_kernel<<<dim3(16, B_ * H_), 256, 0, stream>>>(qh, kh, vT, ao);
    gemm_bt<float><<<dim3(D_ / 128, BT_ / 128), 256, 0, stream>>>(ao, WoT, bo, out, BT_, D_, D_);
}